// Round 3
// baseline (137.038 us; speedup 1.0000x reference)
//
#include <hip/hip_runtime.h>
#include <math.h>
#include <stdint.h>

// B,K,V,T,S,H = 128,10,50257,20,4,2048; t read from input.
#define NB 128
#define NK 10
#define NV 50257
#define NT 20
#define NS 4
#define NH 2048

// Monotone bijection float -> uint32 (no NaNs in data): preserves order.
// key==0 only for bit pattern 0xFFFFFFFF (negative NaN) -> impossible here,
// so key==0 is a safe "invalid" marker.
__device__ __forceinline__ unsigned key_of(float f) {
    unsigned u = __float_as_uint(f);
    unsigned m = (unsigned)((int)u >> 31) | 0x80000000u;
    return u ^ m;
}
__device__ __forceinline__ float val_of(unsigned k) {
    unsigned m = (k & 0x80000000u) ? 0x80000000u : 0xFFFFFFFFu;
    return __uint_as_float(k ^ m);
}

// ---------------------------------------------------------------------------
// Kernel 1: per-(b,k) row top-10. 4 waves/row; each wave keeps ONE
// wave-uniform top-10 as packed u64 (key<<32 | ~idx: total order =
// (val desc, idx asc) = jax.lax.top_k tie-break). Common path: 8 elements
// per ballot (max8 vs cached threshold). Drain: uniform-lane readlane
// (no ds_bpermute), early-exit bubble insert.
// ---------------------------------------------------------------------------
__global__ __launch_bounds__(256) void topk_rows(const float* __restrict__ lp,
                                                 float* __restrict__ ys,   // (B*K,10)
                                                 int*   __restrict__ ix) { // (B*K,10)
    const int row  = blockIdx.x;
    const int tid  = threadIdx.x;
    const int lane = tid & 63;
    const int wave = tid >> 6;
    const float* rowp = lp + (size_t)row * NV;

    unsigned long long L[10];
#pragma unroll
    for (int j = 0; j < 10; ++j) L[j] = 0ull;
    unsigned thr = 0;  // == (unsigned)(L[9] >> 32)

    // Insert candidate (wave-uniform scalar args). ck==0 -> invalid.
    auto consider = [&](unsigned ck, int cidx) {
        if (ck) {
            unsigned long long cand =
                ((unsigned long long)ck << 32) | (unsigned)(~(unsigned)cidx);
            if (cand > L[9]) {
                L[9] = cand;
#pragma unroll
                for (int j = 9; j > 0; --j) {
                    if (L[j] > L[j - 1]) {
                        unsigned long long t = L[j - 1]; L[j - 1] = L[j]; L[j] = t;
                    } else break;  // uniform branch
                }
                thr = (unsigned)(L[9] >> 32);
            }
        }
    };

    // One-candidate-per-lane round (prologue/epilogue).
    auto round1 = [&](unsigned k, int idxbase /*uniform*/) {
        unsigned long long m = __ballot(k != 0 && k >= thr);
        while (m) {
            int l = (int)__builtin_ctzll(m);
            m &= m - 1;
            unsigned ck = (unsigned)__builtin_amdgcn_readlane((int)k, l);
            consider(ck, idxbase + l);
        }
    };

    const int head = (int)(((16u - (unsigned)((uintptr_t)rowp & 15u)) & 15u) >> 2);

    // Prologue: idx in [0, head) (head<=3; only wave 0 lanes valid; tid-partitioned).
    {
        unsigned k = (tid < head) ? key_of(rowp[tid]) : 0u;
        if (wave == 0) round1(k, 0);
    }

    const int n4 = (NV - 1 - head) >> 2;

    // Epilogue early (primes threshold a little): [head+4*n4, NV), incl. penalty.
    {
        int idx = head + 4 * n4 + tid;
        bool valid = idx < NV;
        float v = valid ? rowp[idx] : 0.0f;
        if (idx == NV - 1) v -= 1000.0f;
        unsigned k = valid ? key_of(v) : 0u;
        if (wave == 0) round1(k, head + 4 * n4);  // lanes beyond count give k=0
    }

    // Main: 8 elements per lane per iteration (two float4s, 2 loads in flight).
    const float4* rowp4 = (const float4*)(rowp + head);
    for (int j0 = 0; j0 < n4; j0 += 512) {
        const int ja = j0 + tid;
        const int jb = ja + 256;
        unsigned ka0 = 0, ka1 = 0, ka2 = 0, ka3 = 0;
        unsigned kb0 = 0, kb1 = 0, kb2 = 0, kb3 = 0;
        if (ja < n4) {
            float4 a = rowp4[ja];
            ka0 = key_of(a.x); ka1 = key_of(a.y); ka2 = key_of(a.z); ka3 = key_of(a.w);
        }
        if (jb < n4) {
            float4 b = rowp4[jb];
            kb0 = key_of(b.x); kb1 = key_of(b.y); kb2 = key_of(b.z); kb3 = key_of(b.w);
        }
        unsigned ma = max(max(ka0, ka1), max(ka2, ka3));
        unsigned mb = max(max(kb0, kb1), max(kb2, kb3));
        unsigned mk = max(ma, mb);
        unsigned long long m = __ballot(mk != 0 && mk >= thr);
        while (m) {
            int l = (int)__builtin_ctzll(m);
            m &= m - 1;
            const int basea = head + 4 * (j0 + (wave << 6) + l);  // uniform
            const int baseb = basea + 1024;                        // 4*256
            unsigned c;
            c = (unsigned)__builtin_amdgcn_readlane((int)ka0, l); consider(c, basea + 0);
            c = (unsigned)__builtin_amdgcn_readlane((int)ka1, l); consider(c, basea + 1);
            c = (unsigned)__builtin_amdgcn_readlane((int)ka2, l); consider(c, basea + 2);
            c = (unsigned)__builtin_amdgcn_readlane((int)ka3, l); consider(c, basea + 3);
            c = (unsigned)__builtin_amdgcn_readlane((int)kb0, l); consider(c, baseb + 0);
            c = (unsigned)__builtin_amdgcn_readlane((int)kb1, l); consider(c, baseb + 1);
            c = (unsigned)__builtin_amdgcn_readlane((int)kb2, l); consider(c, baseb + 2);
            c = (unsigned)__builtin_amdgcn_readlane((int)kb3, l); consider(c, baseb + 3);
        }
    }

    // Merge 4 wave-lists (40 distinct u64s) by rank-counting.
    __shared__ unsigned long long sm[40];
    if (lane == 0) {
#pragma unroll
        for (int r = 0; r < 10; ++r) sm[wave * 10 + r] = L[r];
    }
    __syncthreads();
    if (tid < 40) {
        unsigned long long my = sm[tid];
        int rank = 0;
#pragma unroll
        for (int j = 0; j < 40; ++j) rank += (sm[j] > my) ? 1 : 0;
        if (rank < 10) {
            unsigned k32 = (unsigned)(my >> 32);
            int idx = (int)(~(unsigned)(my & 0xFFFFFFFFull));
            ys[row * 10 + rank] = val_of(k32);
            ix[row * 10 + rank] = idx;
        }
    }
}

// ---------------------------------------------------------------------------
// Kernel 2: per-batch candidate selection + seq/seq_lp/p outputs.
// ---------------------------------------------------------------------------
__global__ __launch_bounds__(128) void beam_select(
    const float* __restrict__ lp_sum,   // (B,K)
    const float* __restrict__ seq_lp,   // (B,T,K)
    const int*   __restrict__ seq,      // (B,T,K) int32
    const int*   __restrict__ tptr,     // scalar t
    const float* __restrict__ ys,       // (B*K,10)
    const int*   __restrict__ ix,       // (B*K,10)
    float* __restrict__ out_seq,        // (B,T,K) as float
    float* __restrict__ out_seq_lp,     // (B,T,K)
    float* __restrict__ out_p,          // (B,K)
    int*   __restrict__ qsel_out)       // (B,K)
{
    const int b = blockIdx.x;
    const int tid = threadIdx.x;
    const int t = tptr[0];

    __shared__ float sf[100];
    __shared__ int   so[10];
    __shared__ int   sq[10];
    __shared__ int   stok[10];
    __shared__ float sr[10];

    if (tid < 100) {
        int c = tid / 10, q = tid % 10;  // flat f = c*K + q
        sf[tid] = lp_sum[b * 10 + q] + ys[(b * 10 + q) * 10 + c];
    }
    __syncthreads();
    if (tid < 100) {
        float v = sf[tid];
        int rank = 0;
        for (int j = 0; j < 100; ++j) {
            float u = sf[j];
            rank += (u > v || (u == v && j < tid)) ? 1 : 0; // argsort-stable
        }
        if (rank < 10) so[rank] = tid;
    }
    __syncthreads();
    if (tid < 10) {
        int f = so[tid];
        int c = f / 10, q = f % 10;
        sq[tid] = q;
        stok[tid] = ix[(b * 10 + q) * 10 + c];
        sr[tid] = ys[(b * 10 + q) * 10 + c];
        out_p[b * 10 + tid] = sf[f];
        qsel_out[b * 10 + tid] = q;
    }
    __syncthreads();
    for (int i = tid; i < NT * 10; i += 128) {
        int time = i / 10, k = i % 10;
        int qs = sq[k];
        int src_k = (time < t) ? qs : k;
        int   sval = seq[(b * NT + time) * 10 + src_k];
        float lv = seq_lp[(b * NT + time) * 10 + src_k];
        if (time == t) { sval = stok[k]; lv = sr[k]; }
        out_seq[(b * NT + time) * 10 + k]    = (float)sval; // exact: tokens < 2^24
        out_seq_lp[(b * NT + time) * 10 + k] = lv;
    }
}

// ---------------------------------------------------------------------------
// Kernel 3: new_state[b,s,k,:] = state[b,s,q_sel[b,k],:]  (8KB rows, float4)
// ---------------------------------------------------------------------------
__global__ __launch_bounds__(256) void state_gather(
    const float* __restrict__ st,     // (B,S,K,H)
    const int*   __restrict__ qsel,   // (B,K)
    float* __restrict__ out_st)       // (B,S,K,H)
{
    const int row = blockIdx.x;       // b*S*K + s*K + k
    const int k  = row % NK;
    const int bs = row / NK;          // b*S + s
    const int b  = bs / NS;
    const int q  = qsel[b * NK + k];

    const float4* src = (const float4*)(st + ((size_t)bs * NK + q) * NH);
    float4*       dst = (float4*)(out_st + (size_t)row * NH);
    const int tid = threadIdx.x;
    dst[tid]       = src[tid];
    dst[tid + 256] = src[tid + 256];
}

extern "C" void kernel_launch(void* const* d_in, const int* in_sizes, int n_in,
                              void* d_out, int out_size, void* d_ws, size_t ws_size,
                              hipStream_t stream) {
    const float* lp      = (const float*)d_in[0];  // (B,K,V)
    const float* lp_sum  = (const float*)d_in[1];  // (B,K)
    const float* seq_lp  = (const float*)d_in[2];  // (B,T,K)
    const float* st      = (const float*)d_in[3];  // (B,S,K,H)
    const int*   seq     = (const int*)d_in[4];    // (B,T,K)
    const int*   tptr    = (const int*)d_in[5];    // scalar t

    float* out        = (float*)d_out;
    float* out_seq    = out;                         // 25600
    float* out_seq_lp = out + NB * NT * NK;          // +25600
    float* out_p      = out + 2 * NB * NT * NK;      // +1280
    float* out_st     = out + 2 * NB * NT * NK + NB * NK;

    float* ws_ys   = (float*)d_ws;                   // 12800 floats
    int*   ws_ix   = (int*)((char*)d_ws + 51200);    // 12800 ints
    int*   ws_qsel = (int*)((char*)d_ws + 102400);   // 1280 ints

    topk_rows<<<NB * NK, 256, 0, stream>>>(lp, ws_ys, ws_ix);
    beam_select<<<NB, 128, 0, stream>>>(lp_sum, seq_lp, seq, tptr, ws_ys, ws_ix,
                                        out_seq, out_seq_lp, out_p, ws_qsel);
    state_gather<<<NB * NS * NK, 256, 0, stream>>>(st, ws_qsel, out_st);
}

// Round 4
// 69.345 us; speedup vs baseline: 1.9762x; 1.9762x over previous
//
#include <hip/hip_runtime.h>
#include <math.h>
#include <stdint.h>

// B,K,V,T,S,H = 128,10,50257,20,4,2048; t read from input.
#define NB 128
#define NK 10
#define NV 50257
#define NT 20
#define NS 4
#define NH 2048

#define QCAP 576   // = QTRIG + 512 (max appends/iter) + 16 slack -> no overflow
#define QTRIG 48

// Monotone bijection float->u32 (no NaNs in data). key==0 unreachable.
__device__ __forceinline__ unsigned key_of(float f) {
    unsigned u = __float_as_uint(f);
    unsigned m = (unsigned)((int)u >> 31) | 0x80000000u;
    return u ^ m;
}
__device__ __forceinline__ float val_of(unsigned k) {
    unsigned m = (k & 0x80000000u) ? 0x80000000u : 0xFFFFFFFFu;
    return __uint_as_float(k ^ m);
}
__device__ __forceinline__ float rdlanef(float v, int l) {
    return __uint_as_float((unsigned)__builtin_amdgcn_readlane((int)__float_as_uint(v), l));
}

// ---------------------------------------------------------------------------
// Kernel 1: per-(b,k) row top-10. 4 waves/row. Safe-threshold filter + LDS
// candidate queue + lazy exact compaction. Common path per 8 elems:
// 7 fmax + 1 cmp + ballot. No online top-10 maintenance (no SALU chain).
// ---------------------------------------------------------------------------
__global__ __launch_bounds__(256) void topk_rows(const float* __restrict__ lp,
                                                 float* __restrict__ ys,   // (B*K,10)
                                                 int*   __restrict__ ix) { // (B*K,10)
    const int row  = blockIdx.x;
    const int tid  = threadIdx.x;
    const int lane = tid & 63;
    const int wave = tid >> 6;
    const float* rowp = lp + (size_t)row * NV;

    __shared__ unsigned long long Q[4][QCAP];
    __shared__ int qcnt[4];

    if (lane == 0) qcnt[wave] = 0;
    __threadfence_block();

    float thr = -INFINITY;

    auto lane_append = [&](float v, int idx) {
        if (v >= thr) {
            int p = atomicAdd(&qcnt[wave], 1);
            Q[wave][p] = ((unsigned long long)key_of(v) << 32) | (unsigned)(~(unsigned)idx);
        }
    };

    // Wave-local exact top-10 of queue via rank-count; leaves Q[0..9] sorted
    // desc, count=10, thr = 10th value. Only called when cnt >= 10.
    auto compact = [&]() {
        __threadfence_block();
        int cnt = qcnt[wave];                 // wave-uniform broadcast read
        if (cnt > 10) {
            if (cnt <= 64) {                  // common case
                unsigned long long mine = (lane < cnt) ? Q[wave][lane] : 0ull;
                int rk = 0;
                for (int j = 0; j < cnt; ++j)
                    rk += (Q[wave][j] > mine) ? 1 : 0;   // u64 distinct -> no ties
                __threadfence_block();                   // all reads done (lockstep)
                if (lane < cnt && rk < 10) Q[wave][rk] = mine;
            } else {                          // rare big-dump path
                unsigned long long mine[9];
                int rk[9];
#pragma unroll
                for (int s = 0; s < 9; ++s) {
                    int e = lane + (s << 6);
                    mine[s] = (e < cnt) ? Q[wave][e] : 0ull;
                    rk[s] = 0;
                }
                for (int j = 0; j < cnt; ++j) {
                    unsigned long long qv = Q[wave][j];
#pragma unroll
                    for (int s = 0; s < 9; ++s) rk[s] += (qv > mine[s]) ? 1 : 0;
                }
                __threadfence_block();
#pragma unroll
                for (int s = 0; s < 9; ++s) {
                    int e = lane + (s << 6);
                    if (e < cnt && rk[s] < 10) Q[wave][rk[s]] = mine[s];
                }
            }
            if (lane == 0) qcnt[wave] = 10;
            __threadfence_block();
            thr = val_of((unsigned)(Q[wave][9] >> 32));
        }
    };

    auto process8 = [&](float4 a, float4 b, int basea) {
        float m8 = fmaxf(fmaxf(fmaxf(a.x, a.y), fmaxf(a.z, a.w)),
                         fmaxf(fmaxf(b.x, b.y), fmaxf(b.z, b.w)));
        if (__ballot(m8 >= thr)) {            // rare after priming
            lane_append(a.x, basea + 0);
            lane_append(a.y, basea + 1);
            lane_append(a.z, basea + 2);
            lane_append(a.w, basea + 3);
            lane_append(b.x, basea + 1024);
            lane_append(b.y, basea + 1025);
            lane_append(b.z, basea + 1026);
            lane_append(b.w, basea + 1027);
            __threadfence_block();
            if (qcnt[wave] >= QTRIG) compact();
        }
    };

    const int head = (int)(((16u - (unsigned)((uintptr_t)rowp & 15u)) & 15u) >> 2);
    const int n4 = (NV - 1 - head) >> 2;      // float4s; last element left to tail
    const int NFULL = n4 >> 9;                // full 512-f4 iterations (24)
    const float4* rowp4 = (const float4*)(rowp + head);

    // ---- iteration 0 + threshold priming ----
    float4 a0 = rowp4[tid];
    float4 b0 = rowp4[tid + 256];
    float4 pa = rowp4[512 + tid];             // preload iter 1
    float4 pb = rowp4[768 + tid];

    float m8 = fmaxf(fmaxf(fmaxf(a0.x, a0.y), fmaxf(a0.z, a0.w)),
                     fmaxf(fmaxf(b0.x, b0.y), fmaxf(b0.z, b0.w)));
    // rank of my max8 among the wave's 64 (desc, lane-asc ties) -> permutation
    int rank = 0;
    for (int j = 0; j < 64; ++j) {
        float o = rdlanef(m8, j);
        rank += ((o > m8) || (o == m8 && j < lane)) ? 1 : 0;
    }
    // thr = 10th-largest lane-max8. SAFE: the 10 top lanes each hold an
    // element (their max8) >= thr -> >=10 elements >= thr among first 512.
    {
        unsigned long long b9 = __ballot(rank == 9);
        int l9 = (int)__builtin_ctzll(b9);
        thr = rdlanef(m8, l9);
    }
    {   // iter-0 appends (>=10 by construction)
        int basea = head + 4 * tid;
        lane_append(a0.x, basea + 0);
        lane_append(a0.y, basea + 1);
        lane_append(a0.z, basea + 2);
        lane_append(a0.w, basea + 3);
        lane_append(b0.x, basea + 1024);
        lane_append(b0.y, basea + 1025);
        lane_append(b0.z, basea + 1026);
        lane_append(b0.w, basea + 1027);
        __threadfence_block();
        if (qcnt[wave] >= QTRIG) compact();
    }

    // ---- main pipelined loop: loads for it+1 issued before processing it ----
    for (int it = 1; it < NFULL; ++it) {
        float4 ca = pa, cb = pb;
        int nit = (it + 1 < NFULL) ? it + 1 : it;   // clamp (harmless reload)
        pa = rowp4[(nit << 9) + tid];
        pb = rowp4[(nit << 9) + 256 + tid];
        process8(ca, cb, head + 4 * ((it << 9) + tid));
    }
    // remainder float4s: [NFULL*512, n4)
    {
        int ja = (NFULL << 9) + tid;
        int jb = ja + 256;
        float4 a = (ja < n4) ? rowp4[ja]
                             : make_float4(-INFINITY, -INFINITY, -INFINITY, -INFINITY);
        float4 b = (jb < n4) ? rowp4[jb]
                             : make_float4(-INFINITY, -INFINITY, -INFINITY, -INFINITY);
        process8(a, b, head + 4 * ja);
    }
    // scalar head + tail (incl. penalized last element) on wave 0
    if (wave == 0) {
        if (lane < head) lane_append(rowp[lane], lane);
        int idx = head + 4 * n4 + lane;
        if (idx < NV) {
            float v = rowp[idx];
            if (idx == NV - 1) v -= 1000.0f;
            lane_append(v, idx);
        }
    }

    compact();                                 // per-wave exact top-10
    __syncthreads();

    // merge 4 wave top-10s (40 distinct u64s) by rank-count
    if (tid < 40) {
        int w = tid / 10, r = tid - w * 10;
        unsigned long long my = Q[w][r];
        int rnk = 0;
#pragma unroll
        for (int w2 = 0; w2 < 4; ++w2)
            for (int r2 = 0; r2 < 10; ++r2)
                rnk += (Q[w2][r2] > my) ? 1 : 0;
        if (rnk < 10) {
            ys[row * 10 + rnk] = val_of((unsigned)(my >> 32));
            ix[row * 10 + rnk] = (int)(~(unsigned)(my & 0xFFFFFFFFull));
        }
    }
}

// ---------------------------------------------------------------------------
// Kernel 2: per-batch candidate selection + seq/seq_lp/p outputs.
// ---------------------------------------------------------------------------
__global__ __launch_bounds__(128) void beam_select(
    const float* __restrict__ lp_sum,   // (B,K)
    const float* __restrict__ seq_lp,   // (B,T,K)
    const int*   __restrict__ seq,      // (B,T,K) int32
    const int*   __restrict__ tptr,     // scalar t
    const float* __restrict__ ys,       // (B*K,10)
    const int*   __restrict__ ix,       // (B*K,10)
    float* __restrict__ out_seq,        // (B,T,K) as float
    float* __restrict__ out_seq_lp,     // (B,T,K)
    float* __restrict__ out_p,          // (B,K)
    int*   __restrict__ qsel_out)       // (B,K)
{
    const int b = blockIdx.x;
    const int tid = threadIdx.x;
    const int t = tptr[0];

    __shared__ float sf[100];
    __shared__ int   so[10];
    __shared__ int   sq[10];
    __shared__ int   stok[10];
    __shared__ float sr[10];

    if (tid < 100) {
        int c = tid / 10, q = tid % 10;  // flat f = c*K + q
        sf[tid] = lp_sum[b * 10 + q] + ys[(b * 10 + q) * 10 + c];
    }
    __syncthreads();
    if (tid < 100) {
        float v = sf[tid];
        int rank = 0;
        for (int j = 0; j < 100; ++j) {
            float u = sf[j];
            rank += (u > v || (u == v && j < tid)) ? 1 : 0; // argsort-stable
        }
        if (rank < 10) so[rank] = tid;
    }
    __syncthreads();
    if (tid < 10) {
        int f = so[tid];
        int c = f / 10, q = f % 10;
        sq[tid] = q;
        stok[tid] = ix[(b * 10 + q) * 10 + c];
        sr[tid] = ys[(b * 10 + q) * 10 + c];
        out_p[b * 10 + tid] = sf[f];
        qsel_out[b * 10 + tid] = q;
    }
    __syncthreads();
    for (int i = tid; i < NT * 10; i += 128) {
        int time = i / 10, k = i % 10;
        int qs = sq[k];
        int src_k = (time < t) ? qs : k;
        int   sval = seq[(b * NT + time) * 10 + src_k];
        float lv = seq_lp[(b * NT + time) * 10 + src_k];
        if (time == t) { sval = stok[k]; lv = sr[k]; }
        out_seq[(b * NT + time) * 10 + k]    = (float)sval; // exact: tokens < 2^24
        out_seq_lp[(b * NT + time) * 10 + k] = lv;
    }
}

// ---------------------------------------------------------------------------
// Kernel 3: new_state[b,s,k,:] = state[b,s,q_sel[b,k],:]  (8KB rows, float4)
// ---------------------------------------------------------------------------
__global__ __launch_bounds__(256) void state_gather(
    const float* __restrict__ st,     // (B,S,K,H)
    const int*   __restrict__ qsel,   // (B,K)
    float* __restrict__ out_st)       // (B,S,K,H)
{
    const int row = blockIdx.x;       // b*S*K + s*K + k
    const int k  = row % NK;
    const int bs = row / NK;          // b*S + s
    const int b  = bs / NS;
    const int q  = qsel[b * NK + k];

    const float4* src = (const float4*)(st + ((size_t)bs * NK + q) * NH);
    float4*       dst = (float4*)(out_st + (size_t)row * NH);
    const int tid = threadIdx.x;
    dst[tid]       = src[tid];
    dst[tid + 256] = src[tid + 256];
}

extern "C" void kernel_launch(void* const* d_in, const int* in_sizes, int n_in,
                              void* d_out, int out_size, void* d_ws, size_t ws_size,
                              hipStream_t stream) {
    const float* lp      = (const float*)d_in[0];  // (B,K,V)
    const float* lp_sum  = (const float*)d_in[1];  // (B,K)
    const float* seq_lp  = (const float*)d_in[2];  // (B,T,K)
    const float* st      = (const float*)d_in[3];  // (B,S,K,H)
    const int*   seq     = (const int*)d_in[4];    // (B,T,K)
    const int*   tptr    = (const int*)d_in[5];    // scalar t

    float* out        = (float*)d_out;
    float* out_seq    = out;                         // 25600
    float* out_seq_lp = out + NB * NT * NK;          // +25600
    float* out_p      = out + 2 * NB * NT * NK;      // +1280
    float* out_st     = out + 2 * NB * NT * NK + NB * NK;

    float* ws_ys   = (float*)d_ws;                   // 12800 floats
    int*   ws_ix   = (int*)((char*)d_ws + 51200);    // 12800 ints
    int*   ws_qsel = (int*)((char*)d_ws + 102400);   // 1280 ints

    topk_rows<<<NB * NK, 256, 0, stream>>>(lp, ws_ys, ws_ix);
    beam_select<<<NB, 128, 0, stream>>>(lp_sum, seq_lp, seq, tptr, ws_ys, ws_ix,
                                        out_seq, out_seq_lp, out_p, ws_qsel);
    state_gather<<<NB * NS * NK, 256, 0, stream>>>(st, ws_qsel, out_st);
}

// Round 5
// 68.926 us; speedup vs baseline: 1.9882x; 1.0061x over previous
//
#include <hip/hip_runtime.h>
#include <math.h>
#include <stdint.h>

// B,K,V,T,S,H = 128,10,50257,20,4,2048; t read from input.
#define NB 128
#define NK 10
#define NV 50257
#define NT 20
#define NS 4
#define NH 2048

#define QCAP 576   // = QTRIG + 512 (max appends/iter) + slack -> no overflow
#define QTRIG 48

// Monotone bijection float->u32 (no NaNs in data). key==0 unreachable.
__device__ __forceinline__ unsigned key_of(float f) {
    unsigned u = __float_as_uint(f);
    unsigned m = (unsigned)((int)u >> 31) | 0x80000000u;
    return u ^ m;
}
__device__ __forceinline__ float val_of(unsigned k) {
    unsigned m = (k & 0x80000000u) ? 0x80000000u : 0xFFFFFFFFu;
    return __uint_as_float(k ^ m);
}
__device__ __forceinline__ float rdlanef(float v, int l) {
    return __uint_as_float((unsigned)__builtin_amdgcn_readlane((int)__float_as_uint(v), l));
}

// ---------------------------------------------------------------------------
// Kernel 1: per-(b,k) row top-10. 4 waves/row. Safe-threshold filter + LDS
// candidate queue + lazy exact compaction.
// ---------------------------------------------------------------------------
__global__ __launch_bounds__(256) void topk_rows(const float* __restrict__ lp,
                                                 float* __restrict__ ys,   // (B*K,10)
                                                 int*   __restrict__ ix) { // (B*K,10)
    const int row  = blockIdx.x;
    const int tid  = threadIdx.x;
    const int lane = tid & 63;
    const int wave = tid >> 6;
    const float* rowp = lp + (size_t)row * NV;

    __shared__ unsigned long long Q[4][QCAP];
    __shared__ int qcnt[4];

    if (lane == 0) qcnt[wave] = 0;
    __threadfence_block();

    float thr = -INFINITY;

    auto lane_append = [&](float v, int idx) {
        if (v >= thr) {
            int p = atomicAdd(&qcnt[wave], 1);
            Q[wave][p] = ((unsigned long long)key_of(v) << 32) | (unsigned)(~(unsigned)idx);
        }
    };

    // Wave-local exact top-10 via rank-count; leaves Q[0..9] sorted desc,
    // count=10, thr = 10th value.
    auto compact = [&]() {
        __threadfence_block();
        int cnt = qcnt[wave];
        if (cnt > 10) {
            if (cnt <= 64) {
                unsigned long long mine = (lane < cnt) ? Q[wave][lane] : 0ull;
                int rk = 0;
                for (int j = 0; j < cnt; ++j)
                    rk += (Q[wave][j] > mine) ? 1 : 0;   // u64s distinct
                __threadfence_block();
                if (lane < cnt && rk < 10) Q[wave][rk] = mine;
            } else {
                unsigned long long mine[9];
                int rk[9];
#pragma unroll
                for (int s = 0; s < 9; ++s) {
                    int e = lane + (s << 6);
                    mine[s] = (e < cnt) ? Q[wave][e] : 0ull;
                    rk[s] = 0;
                }
                for (int j = 0; j < cnt; ++j) {
                    unsigned long long qv = Q[wave][j];
#pragma unroll
                    for (int s = 0; s < 9; ++s) rk[s] += (qv > mine[s]) ? 1 : 0;
                }
                __threadfence_block();
#pragma unroll
                for (int s = 0; s < 9; ++s) {
                    int e = lane + (s << 6);
                    if (e < cnt && rk[s] < 10) Q[wave][rk[s]] = mine[s];
                }
            }
            if (lane == 0) qcnt[wave] = 10;
            __threadfence_block();
            thr = val_of((unsigned)(Q[wave][9] >> 32));
        }
    };

    auto process8 = [&](float4 a, float4 b, int basea) {
        float m8 = fmaxf(fmaxf(fmaxf(a.x, a.y), fmaxf(a.z, a.w)),
                         fmaxf(fmaxf(b.x, b.y), fmaxf(b.z, b.w)));
        if (__ballot(m8 >= thr)) {            // rare after priming
            lane_append(a.x, basea + 0);
            lane_append(a.y, basea + 1);
            lane_append(a.z, basea + 2);
            lane_append(a.w, basea + 3);
            lane_append(b.x, basea + 1024);
            lane_append(b.y, basea + 1025);
            lane_append(b.z, basea + 1026);
            lane_append(b.w, basea + 1027);
            __threadfence_block();
            if (qcnt[wave] >= QTRIG) compact();
        }
    };

    const int head = (int)(((16u - (unsigned)((uintptr_t)rowp & 15u)) & 15u) >> 2);
    const int n4 = (NV - 1 - head) >> 2;      // float4s; last element in tail
    const int NFULL = n4 >> 9;                // full 512-f4 iterations
    const float4* rowp4 = (const float4*)(rowp + head);

    // ---- iteration 0 + threshold priming ----
    float4 a0 = rowp4[tid];
    float4 b0 = rowp4[tid + 256];
    float4 pa = rowp4[512 + tid];             // preload iter 1
    float4 pb = rowp4[768 + tid];

    float m8 = fmaxf(fmaxf(fmaxf(a0.x, a0.y), fmaxf(a0.z, a0.w)),
                     fmaxf(fmaxf(b0.x, b0.y), fmaxf(b0.z, b0.w)));
    int rank = 0;
    for (int j = 0; j < 64; ++j) {
        float o = rdlanef(m8, j);
        rank += ((o > m8) || (o == m8 && j < lane)) ? 1 : 0;
    }
    // thr = 10th-largest lane-max8: >=10 elements >= thr among first 512.
    {
        unsigned long long b9 = __ballot(rank == 9);
        int l9 = (int)__builtin_ctzll(b9);
        thr = rdlanef(m8, l9);
    }
    {
        int basea = head + 4 * tid;
        lane_append(a0.x, basea + 0);
        lane_append(a0.y, basea + 1);
        lane_append(a0.z, basea + 2);
        lane_append(a0.w, basea + 3);
        lane_append(b0.x, basea + 1024);
        lane_append(b0.y, basea + 1025);
        lane_append(b0.z, basea + 1026);
        lane_append(b0.w, basea + 1027);
        __threadfence_block();
        if (qcnt[wave] >= QTRIG) compact();
    }

    // ---- main pipelined loop; guarded prefetch (no wasted reload) ----
    for (int it = 1; it < NFULL; ++it) {
        float4 ca = pa, cb = pb;
        if (it + 1 < NFULL) {
            pa = rowp4[((it + 1) << 9) + tid];
            pb = rowp4[((it + 1) << 9) + 256 + tid];
        }
        process8(ca, cb, head + 4 * ((it << 9) + tid));
    }
    // remainder float4s: [NFULL*512, n4)
    {
        int ja = (NFULL << 9) + tid;
        int jb = ja + 256;
        float4 a = (ja < n4) ? rowp4[ja]
                             : make_float4(-INFINITY, -INFINITY, -INFINITY, -INFINITY);
        float4 b = (jb < n4) ? rowp4[jb]
                             : make_float4(-INFINITY, -INFINITY, -INFINITY, -INFINITY);
        process8(a, b, head + 4 * ja);
    }
    // scalar head + tail (incl. penalized last element) on wave 0
    if (wave == 0) {
        if (lane < head) lane_append(rowp[lane], lane);
        int idx = head + 4 * n4 + lane;
        if (idx < NV) {
            float v = rowp[idx];
            if (idx == NV - 1) v -= 1000.0f;
            lane_append(v, idx);
        }
    }

    compact();
    __syncthreads();

    // merge 4 wave top-10s (40 distinct u64s) by rank-count
    if (tid < 40) {
        int w = tid / 10, r = tid - w * 10;
        unsigned long long my = Q[w][r];
        int rnk = 0;
#pragma unroll
        for (int w2 = 0; w2 < 4; ++w2)
            for (int r2 = 0; r2 < 10; ++r2)
                rnk += (Q[w2][r2] > my) ? 1 : 0;
        if (rnk < 10) {
            ys[row * 10 + rnk] = val_of((unsigned)(my >> 32));
            ix[row * 10 + rnk] = (int)(~(unsigned)(my & 0xFFFFFFFFull));
        }
    }
}

// ---------------------------------------------------------------------------
// Kernel 2 (fused select + gather): one block per output state row
// (b,s,k). Each block redundantly rank-counts the 100 candidates of its
// batch (cheap, L2-cached), then gathers its 8KB state row. The (s==0,k==0)
// block of each batch additionally writes seq / seq_lp / p.
// ---------------------------------------------------------------------------
__global__ __launch_bounds__(256) void select_gather(
    const float* __restrict__ lp_sum,   // (B,K)
    const float* __restrict__ seq_lp,   // (B,T,K)
    const int*   __restrict__ seq,      // (B,T,K) int32
    const int*   __restrict__ tptr,     // scalar t
    const float* __restrict__ ys,       // (B*K,10)
    const int*   __restrict__ ix,       // (B*K,10)
    const float* __restrict__ st,       // (B,S,K,H)
    float* __restrict__ out_seq,        // (B,T,K) as float
    float* __restrict__ out_seq_lp,     // (B,T,K)
    float* __restrict__ out_p,          // (B,K)
    float* __restrict__ out_st)         // (B,S,K,H)
{
    const int row = blockIdx.x;          // b*40 + s*10 + k
    const int b   = row / (NS * NK);
    const int rem = row - b * (NS * NK);
    const int s   = rem / NK;
    const int k   = rem - s * NK;
    const int tid = threadIdx.x;

    __shared__ float sf[100];
    __shared__ int   so[10];
    __shared__ int   sq[10];
    __shared__ int   stok[10];
    __shared__ float sr[10];

    if (tid < 100) {
        int c = tid / 10, q = tid % 10;  // flat f = c*K + q
        sf[tid] = lp_sum[b * 10 + q] + ys[(b * 10 + q) * 10 + c];
    }
    __syncthreads();
    if (tid < 100) {
        float v = sf[tid];
        int rank = 0;
        for (int j = 0; j < 100; ++j) {
            float u = sf[j];
            rank += (u > v || (u == v && j < tid)) ? 1 : 0; // argsort-stable
        }
        if (rank < 10) so[rank] = tid;
    }
    __syncthreads();

    // --- gather this block's state row ---
    const int q = so[k] % 10;
    const float4* src = (const float4*)(st + ((size_t)(b * NS + s) * NK + q) * NH);
    float4*       dst = (float4*)(out_st + (size_t)row * NH);
    dst[tid]       = src[tid];
    dst[tid + 256] = src[tid + 256];

    // --- one block per batch writes seq outputs (block-uniform branch) ---
    if (s == 0 && k == 0) {
        const int t = tptr[0];
        if (tid < 10) {
            int f = so[tid];
            int c = f / 10, qq = f % 10;
            sq[tid]   = qq;
            stok[tid] = ix[(b * 10 + qq) * 10 + c];
            sr[tid]   = ys[(b * 10 + qq) * 10 + c];
            out_p[b * 10 + tid] = sf[f];
        }
        __syncthreads();
        if (tid < NT * NK) {                 // 200 < 256: single pass
            int time = tid / 10, kk = tid % 10;
            int qs = sq[kk];
            int src_k = (time < t) ? qs : kk;
            int   sval = seq[(b * NT + time) * 10 + src_k];
            float lv = seq_lp[(b * NT + time) * 10 + src_k];
            if (time == t) { sval = stok[kk]; lv = sr[kk]; }
            out_seq[(b * NT + time) * 10 + kk]    = (float)sval; // exact <2^24
            out_seq_lp[(b * NT + time) * 10 + kk] = lv;
        }
    }
}

extern "C" void kernel_launch(void* const* d_in, const int* in_sizes, int n_in,
                              void* d_out, int out_size, void* d_ws, size_t ws_size,
                              hipStream_t stream) {
    const float* lp      = (const float*)d_in[0];  // (B,K,V)
    const float* lp_sum  = (const float*)d_in[1];  // (B,K)
    const float* seq_lp  = (const float*)d_in[2];  // (B,T,K)
    const float* st      = (const float*)d_in[3];  // (B,S,K,H)
    const int*   seq     = (const int*)d_in[4];    // (B,T,K)
    const int*   tptr    = (const int*)d_in[5];    // scalar t

    float* out        = (float*)d_out;
    float* out_seq    = out;                         // 25600
    float* out_seq_lp = out + NB * NT * NK;          // +25600
    float* out_p      = out + 2 * NB * NT * NK;      // +1280
    float* out_st     = out + 2 * NB * NT * NK + NB * NK;

    float* ws_ys   = (float*)d_ws;                   // 12800 floats
    int*   ws_ix   = (int*)((char*)d_ws + 51200);    // 12800 ints

    topk_rows<<<NB * NK, 256, 0, stream>>>(lp, ws_ys, ws_ix);
    select_gather<<<NB * NS * NK, 256, 0, stream>>>(
        lp_sum, seq_lp, seq, tptr, ws_ys, ws_ix, st,
        out_seq, out_seq_lp, out_p, out_st);
}

// Round 6
// 64.876 us; speedup vs baseline: 2.1123x; 1.0624x over previous
//
#include <hip/hip_runtime.h>
#include <math.h>
#include <stdint.h>

// B,K,V,T,S,H = 128,10,50257,20,4,2048; t read from input.
#define NB 128
#define NK 10
#define NV 50257
#define NT 20
#define NS 4
#define NH 2048

#define QCAP 576   // = QTRIG + 512 (max appends/iter) + slack -> no overflow
#define QTRIG 48

// Monotone bijection float->u32 (no NaNs in data). key==0 unreachable.
__device__ __forceinline__ unsigned key_of(float f) {
    unsigned u = __float_as_uint(f);
    unsigned m = (unsigned)((int)u >> 31) | 0x80000000u;
    return u ^ m;
}
__device__ __forceinline__ float val_of(unsigned k) {
    unsigned m = (k & 0x80000000u) ? 0x80000000u : 0xFFFFFFFFu;
    return __uint_as_float(k ^ m);
}
__device__ __forceinline__ float rdlanef(float v, int l) {
    return __uint_as_float((unsigned)__builtin_amdgcn_readlane((int)__float_as_uint(v), l));
}

// ---------------------------------------------------------------------------
// Kernel 1: per-(b,k) row top-10. 4 waves/row. Safe-threshold filter + LDS
// candidate queue + lazy exact compaction. 2-deep load pipeline (4 dwordx4
// in flight per lane) for latency tolerance.
// ---------------------------------------------------------------------------
__global__ __launch_bounds__(256) void topk_rows(const float* __restrict__ lp,
                                                 float* __restrict__ ys,   // (B*K,10)
                                                 int*   __restrict__ ix) { // (B*K,10)
    const int row  = blockIdx.x;
    const int tid  = threadIdx.x;
    const int lane = tid & 63;
    const int wave = tid >> 6;
    const float* rowp = lp + (size_t)row * NV;

    __shared__ unsigned long long Q[4][QCAP];
    __shared__ int qcnt[4];

    if (lane == 0) qcnt[wave] = 0;
    __threadfence_block();

    float thr = -INFINITY;

    auto lane_append = [&](float v, int idx) {
        if (v >= thr) {
            int p = atomicAdd(&qcnt[wave], 1);
            Q[wave][p] = ((unsigned long long)key_of(v) << 32) | (unsigned)(~(unsigned)idx);
        }
    };

    // Wave-local exact top-10 via rank-count; leaves Q[0..9] sorted desc,
    // count=10, thr = 10th value.
    auto compact = [&]() {
        __threadfence_block();
        int cnt = qcnt[wave];
        if (cnt > 10) {
            if (cnt <= 64) {
                unsigned long long mine = (lane < cnt) ? Q[wave][lane] : 0ull;
                int rk = 0;
                for (int j = 0; j < cnt; ++j)
                    rk += (Q[wave][j] > mine) ? 1 : 0;   // u64s distinct
                __threadfence_block();
                if (lane < cnt && rk < 10) Q[wave][rk] = mine;
            } else {
                unsigned long long mine[9];
                int rk[9];
#pragma unroll
                for (int s = 0; s < 9; ++s) {
                    int e = lane + (s << 6);
                    mine[s] = (e < cnt) ? Q[wave][e] : 0ull;
                    rk[s] = 0;
                }
                for (int j = 0; j < cnt; ++j) {
                    unsigned long long qv = Q[wave][j];
#pragma unroll
                    for (int s = 0; s < 9; ++s) rk[s] += (qv > mine[s]) ? 1 : 0;
                }
                __threadfence_block();
#pragma unroll
                for (int s = 0; s < 9; ++s) {
                    int e = lane + (s << 6);
                    if (e < cnt && rk[s] < 10) Q[wave][rk[s]] = mine[s];
                }
            }
            if (lane == 0) qcnt[wave] = 10;
            __threadfence_block();
            thr = val_of((unsigned)(Q[wave][9] >> 32));
        }
    };

    auto process8 = [&](float4 a, float4 b, int basea) {
        float m8 = fmaxf(fmaxf(fmaxf(a.x, a.y), fmaxf(a.z, a.w)),
                         fmaxf(fmaxf(b.x, b.y), fmaxf(b.z, b.w)));
        if (__ballot(m8 >= thr)) {            // rare after priming
            lane_append(a.x, basea + 0);
            lane_append(a.y, basea + 1);
            lane_append(a.z, basea + 2);
            lane_append(a.w, basea + 3);
            lane_append(b.x, basea + 1024);
            lane_append(b.y, basea + 1025);
            lane_append(b.z, basea + 1026);
            lane_append(b.w, basea + 1027);
            __threadfence_block();
            if (qcnt[wave] >= QTRIG) compact();
        }
    };

    const int head = (int)(((16u - (unsigned)((uintptr_t)rowp & 15u)) & 15u) >> 2);
    const int n4 = (NV - 1 - head) >> 2;      // float4s; last element in tail
    const int NFULL = n4 >> 9;                // full 512-f4 iterations (24)
    const float4* rowp4 = (const float4*)(rowp + head);

    // ---- iteration 0 + threshold priming; 2-deep prefetch ----
    float4 a0  = rowp4[tid];
    float4 b0  = rowp4[tid + 256];
    float4 p0a = rowp4[512 + tid];            // data for it=1
    float4 p0b = rowp4[768 + tid];
    float4 p1a = rowp4[1024 + tid];           // data for it=2 (NFULL >= 3 always)
    float4 p1b = rowp4[1280 + tid];

    float m8 = fmaxf(fmaxf(fmaxf(a0.x, a0.y), fmaxf(a0.z, a0.w)),
                     fmaxf(fmaxf(b0.x, b0.y), fmaxf(b0.z, b0.w)));
    int rank = 0;
    for (int j = 0; j < 64; ++j) {
        float o = rdlanef(m8, j);
        rank += ((o > m8) || (o == m8 && j < lane)) ? 1 : 0;
    }
    // thr = 10th-largest lane-max8: >=10 elements >= thr among first 512.
    {
        unsigned long long b9 = __ballot(rank == 9);
        int l9 = (int)__builtin_ctzll(b9);
        thr = rdlanef(m8, l9);
    }
    {
        int basea = head + 4 * tid;
        lane_append(a0.x, basea + 0);
        lane_append(a0.y, basea + 1);
        lane_append(a0.z, basea + 2);
        lane_append(a0.w, basea + 3);
        lane_append(b0.x, basea + 1024);
        lane_append(b0.y, basea + 1025);
        lane_append(b0.z, basea + 1026);
        lane_append(b0.w, basea + 1027);
        __threadfence_block();
        if (qcnt[wave] >= QTRIG) compact();
    }

    // ---- main loop: consume p0 (data for it), shift p1->p0, prefetch it+2 ----
    for (int it = 1; it < NFULL; ++it) {
        float4 ca = p0a, cb = p0b;
        p0a = p1a; p0b = p1b;
        if (it + 2 < NFULL) {
            p1a = rowp4[((it + 2) << 9) + tid];
            p1b = rowp4[((it + 2) << 9) + 256 + tid];
        }
        process8(ca, cb, head + 4 * ((it << 9) + tid));
    }
    // remainder float4s: [NFULL*512, n4)
    {
        int ja = (NFULL << 9) + tid;
        int jb = ja + 256;
        float4 a = (ja < n4) ? rowp4[ja]
                             : make_float4(-INFINITY, -INFINITY, -INFINITY, -INFINITY);
        float4 b = (jb < n4) ? rowp4[jb]
                             : make_float4(-INFINITY, -INFINITY, -INFINITY, -INFINITY);
        process8(a, b, head + 4 * ja);
    }
    // scalar head + tail (incl. penalized last element) on wave 0
    if (wave == 0) {
        if (lane < head) lane_append(rowp[lane], lane);
        int idx = head + 4 * n4 + lane;
        if (idx < NV) {
            float v = rowp[idx];
            if (idx == NV - 1) v -= 1000.0f;
            lane_append(v, idx);
        }
    }

    compact();
    __syncthreads();

    // merge 4 wave top-10s (40 distinct u64s) by rank-count
    if (tid < 40) {
        int w = tid / 10, r = tid - w * 10;
        unsigned long long my = Q[w][r];
        int rnk = 0;
#pragma unroll
        for (int w2 = 0; w2 < 4; ++w2)
            for (int r2 = 0; r2 < 10; ++r2)
                rnk += (Q[w2][r2] > my) ? 1 : 0;
        if (rnk < 10) {
            ys[row * 10 + rnk] = val_of((unsigned)(my >> 32));
            ix[row * 10 + rnk] = (int)(~(unsigned)(my & 0xFFFFFFFFull));
        }
    }
}

// ---------------------------------------------------------------------------
// Kernel 2 (fused select + gather): one block per (b,s); each block computes
// the batch's selection once, then copies all 10 state rows (2-row unrolled
// -> 4 loads in flight; repeated q_sel rows hit L1). s==0 blocks also write
// seq / seq_lp / p.
// ---------------------------------------------------------------------------
__global__ __launch_bounds__(256) void select_gather(
    const float* __restrict__ lp_sum,   // (B,K)
    const float* __restrict__ seq_lp,   // (B,T,K)
    const int*   __restrict__ seq,      // (B,T,K) int32
    const int*   __restrict__ tptr,     // scalar t
    const float* __restrict__ ys,       // (B*K,10)
    const int*   __restrict__ ix,       // (B*K,10)
    const float* __restrict__ st,       // (B,S,K,H)
    float* __restrict__ out_seq,        // (B,T,K) as float
    float* __restrict__ out_seq_lp,     // (B,T,K)
    float* __restrict__ out_p,          // (B,K)
    float* __restrict__ out_st)         // (B,S,K,H)
{
    const int bs  = blockIdx.x;          // b*NS + s
    const int b   = bs / NS;
    const int s   = bs - b * NS;
    const int tid = threadIdx.x;

    __shared__ float sf[100];
    __shared__ int   so[10];
    __shared__ int   sq[10];
    __shared__ int   stok[10];
    __shared__ float sr[10];

    if (tid < 100) {
        int c = tid / 10, q = tid % 10;  // flat f = c*K + q
        sf[tid] = lp_sum[b * 10 + q] + ys[(b * 10 + q) * 10 + c];
    }
    __syncthreads();
    if (tid < 100) {
        float v = sf[tid];
        int rank = 0;
        for (int j = 0; j < 100; ++j) {
            float u = sf[j];
            rank += (u > v || (u == v && j < tid)) ? 1 : 0; // argsort-stable
        }
        if (rank < 10) so[rank] = tid;
    }
    __syncthreads();

    // --- gather 10 state rows, 2 rows per step (4 loads in flight) ---
    const float* src_base = st + (size_t)bs * NK * NH;
    float*       dst_base = out_st + (size_t)bs * NK * NH;
#pragma unroll
    for (int kk = 0; kk < 10; kk += 2) {
        const int q0 = so[kk] % 10;
        const int q1 = so[kk + 1] % 10;
        const float4* s0 = (const float4*)(src_base + (size_t)q0 * NH);
        const float4* s1 = (const float4*)(src_base + (size_t)q1 * NH);
        float4 x0 = s0[tid];
        float4 x1 = s0[tid + 256];
        float4 y0 = s1[tid];
        float4 y1 = s1[tid + 256];
        float4* d0 = (float4*)(dst_base + (size_t)kk * NH);
        float4* d1 = (float4*)(dst_base + (size_t)(kk + 1) * NH);
        d0[tid]       = x0;
        d0[tid + 256] = x1;
        d1[tid]       = y0;
        d1[tid + 256] = y1;
    }

    // --- one block per batch writes seq outputs (block-uniform branch) ---
    if (s == 0) {
        const int t = tptr[0];
        if (tid < 10) {
            int f = so[tid];
            int c = f / 10, qq = f % 10;
            sq[tid]   = qq;
            stok[tid] = ix[(b * 10 + qq) * 10 + c];
            sr[tid]   = ys[(b * 10 + qq) * 10 + c];
            out_p[b * 10 + tid] = sf[f];
        }
        __syncthreads();
        if (tid < NT * NK) {                 // 200 < 256: single pass
            int time = tid / 10, kk = tid % 10;
            int qs = sq[kk];
            int src_k = (time < t) ? qs : kk;
            int   sval = seq[(b * NT + time) * 10 + src_k];
            float lv = seq_lp[(b * NT + time) * 10 + src_k];
            if (time == t) { sval = stok[kk]; lv = sr[kk]; }
            out_seq[(b * NT + time) * 10 + kk]    = (float)sval; // exact <2^24
            out_seq_lp[(b * NT + time) * 10 + kk] = lv;
        }
    }
}

extern "C" void kernel_launch(void* const* d_in, const int* in_sizes, int n_in,
                              void* d_out, int out_size, void* d_ws, size_t ws_size,
                              hipStream_t stream) {
    const float* lp      = (const float*)d_in[0];  // (B,K,V)
    const float* lp_sum  = (const float*)d_in[1];  // (B,K)
    const float* seq_lp  = (const float*)d_in[2];  // (B,T,K)
    const float* st      = (const float*)d_in[3];  // (B,S,K,H)
    const int*   seq     = (const int*)d_in[4];    // (B,T,K)
    const int*   tptr    = (const int*)d_in[5];    // scalar t

    float* out        = (float*)d_out;
    float* out_seq    = out;                         // 25600
    float* out_seq_lp = out + NB * NT * NK;          // +25600
    float* out_p      = out + 2 * NB * NT * NK;      // +1280
    float* out_st     = out + 2 * NB * NT * NK + NB * NK;

    float* ws_ys   = (float*)d_ws;                   // 12800 floats
    int*   ws_ix   = (int*)((char*)d_ws + 51200);    // 12800 ints

    topk_rows<<<NB * NK, 256, 0, stream>>>(lp, ws_ys, ws_ix);
    select_gather<<<NB * NS, 256, 0, stream>>>(
        lp_sum, seq_lp, seq, tptr, ws_ys, ws_ix, st,
        out_seq, out_seq_lp, out_p, out_st);
}